// Round 1
// baseline (25998.633 us; speedup 1.0000x reference)
//
#include <hip/hip_runtime.h>
#include <cstddef>

#define B_ 128
#define T_ 512
#define I_ 512
#define H_ 1024
#define TH_ (T_ * H_)

// ---------------------------------------------------------------------------
// Kernel 1: xin = x @ Wi^T + bi  written into out's rnn_out region [B,T,H].
// A [M=B*T, K=I] row-major (x), W [N=H, K=I] row-major (Wi). C row-major [M,N].
// Tile 128x128, BK=16, 256 threads, 8x8 micro-tile.
// ---------------------------------------------------------------------------
__global__ __launch_bounds__(256) void k_input_gemm(
    const float* __restrict__ A, const float* __restrict__ W,
    const float* __restrict__ bi, float* __restrict__ C)
{
    const int nb = blockIdx.x;   // 0..7   (N blocks of 128)
    const int mb = blockIdx.y;   // 0..511 (M blocks of 128)
    const int tid = threadIdx.x;
    const int tx = tid & 15;     // 0..15 -> n micro col group
    const int ty = tid >> 4;     // 0..15 -> m micro row group

    __shared__ float As[16][132];  // k-major: As[kk][m], padded row = 132 floats
    __shared__ float Ws[16][132];

    float acc[8][8];
#pragma unroll
    for (int i = 0; i < 8; ++i)
#pragma unroll
        for (int j = 0; j < 8; ++j) acc[i][j] = 0.f;

    const float* Ab = A + (size_t)mb * 128 * I_;
    const float* Wb = W + (size_t)nb * 128 * I_;

    for (int kt = 0; kt < I_; kt += 16) {
        // Load A tile: 128 rows x 16 k = 512 float4, 2 per thread.
        {
            const int r = tid >> 2;       // 0..63
            const int kq = (tid & 3) * 4; // 0,4,8,12
            float4 v0 = *(const float4*)(Ab + (size_t)r * I_ + kt + kq);
            float4 v1 = *(const float4*)(Ab + (size_t)(r + 64) * I_ + kt + kq);
            As[kq + 0][r] = v0.x; As[kq + 1][r] = v0.y;
            As[kq + 2][r] = v0.z; As[kq + 3][r] = v0.w;
            As[kq + 0][r + 64] = v1.x; As[kq + 1][r + 64] = v1.y;
            As[kq + 2][r + 64] = v1.z; As[kq + 3][r + 64] = v1.w;
            float4 w0 = *(const float4*)(Wb + (size_t)r * I_ + kt + kq);
            float4 w1 = *(const float4*)(Wb + (size_t)(r + 64) * I_ + kt + kq);
            Ws[kq + 0][r] = w0.x; Ws[kq + 1][r] = w0.y;
            Ws[kq + 2][r] = w0.z; Ws[kq + 3][r] = w0.w;
            Ws[kq + 0][r + 64] = w1.x; Ws[kq + 1][r + 64] = w1.y;
            Ws[kq + 2][r + 64] = w1.z; Ws[kq + 3][r + 64] = w1.w;
        }
        __syncthreads();

#pragma unroll
        for (int kk = 0; kk < 16; ++kk) {
            float4 a0 = *(const float4*)&As[kk][ty * 8];
            float4 a1 = *(const float4*)&As[kk][ty * 8 + 4];
            float4 b0 = *(const float4*)&Ws[kk][tx * 8];
            float4 b1 = *(const float4*)&Ws[kk][tx * 8 + 4];
            float av[8] = {a0.x, a0.y, a0.z, a0.w, a1.x, a1.y, a1.z, a1.w};
            float bv[8] = {b0.x, b0.y, b0.z, b0.w, b1.x, b1.y, b1.z, b1.w};
#pragma unroll
            for (int i = 0; i < 8; ++i)
#pragma unroll
                for (int j = 0; j < 8; ++j) acc[i][j] += av[i] * bv[j];
        }
        __syncthreads();
    }

    // Epilogue: add bias, store.
    const int n0 = nb * 128 + tx * 8;
    float4 bv0 = *(const float4*)(bi + n0);
    float4 bv1 = *(const float4*)(bi + n0 + 4);
#pragma unroll
    for (int i = 0; i < 8; ++i) {
        const size_t m = (size_t)mb * 128 + ty * 8 + i;
        float4 c0, c1;
        c0.x = acc[i][0] + bv0.x; c0.y = acc[i][1] + bv0.y;
        c0.z = acc[i][2] + bv0.z; c0.w = acc[i][3] + bv0.w;
        c1.x = acc[i][4] + bv1.x; c1.y = acc[i][5] + bv1.y;
        c1.z = acc[i][6] + bv1.z; c1.w = acc[i][7] + bv1.w;
        *(float4*)(C + m * H_ + n0) = c0;
        *(float4*)(C + m * H_ + n0 + 4) = c1;
    }
}

// ---------------------------------------------------------------------------
// Kernel 2: one recurrent step, fused GEMM + clamp, in-place on out.
//   h_t[m][n] = clamp(h_{t-1}[m][n] + xin[m][t][n] + sum_k h_{t-1}[m][k]*Wh[n][k] + bh[n])
// h_{t-1} read from out[:, t-1, :] (or h0 for t=0); xin read from out[:, t, :]
// and overwritten with h_t.
// Grid: (8 m-blocks of 16) x (16 n-blocks of 64). 256 threads, micro 1x4.
// ---------------------------------------------------------------------------
__global__ __launch_bounds__(256) void k_step(
    const float* __restrict__ Wh, const float* __restrict__ bh,
    const float* __restrict__ h0, float* __restrict__ out, int t)
{
    const int mb = blockIdx.x;   // 0..7
    const int nb = blockIdx.y;   // 0..15
    const int tid = threadIdx.x;
    const int tx = tid & 15;     // n = nb*64 + tx*4
    const int ty = tid >> 4;     // m = mb*16 + ty

    __shared__ float hs[64][16];   // k-major: hs[kk][m]
    __shared__ float ws[64][68];   // k-major: ws[kk][n], padded

    const float* hbase;
    size_t hstride;
    if (t == 0) { hbase = h0;                        hstride = 0; }
    else        { hbase = out + (size_t)(t - 1) * H_; hstride = TH_; }

    float acc0 = 0.f, acc1 = 0.f, acc2 = 0.f, acc3 = 0.f;

    const int hr = tid >> 4;        // 0..15 row for h load
    const int kq = (tid & 15) * 4;  // 0..60 k offset for loads

    for (int kt = 0; kt < H_; kt += 64) {
        // h tile: 16 rows x 64 k -> 256 float4, one per thread
        {
            float4 hv = *(const float4*)(hbase + (size_t)(mb * 16 + hr) * hstride + kt + kq);
            hs[kq + 0][hr] = hv.x; hs[kq + 1][hr] = hv.y;
            hs[kq + 2][hr] = hv.z; hs[kq + 3][hr] = hv.w;
        }
        // Wh tile: 64 rows x 64 k -> 1024 float4, four per thread
#pragma unroll
        for (int p = 0; p < 4; ++p) {
            const int wr = hr + p * 16;  // 0..63
            float4 wv = *(const float4*)(Wh + (size_t)(nb * 64 + wr) * H_ + kt + kq);
            ws[kq + 0][wr] = wv.x; ws[kq + 1][wr] = wv.y;
            ws[kq + 2][wr] = wv.z; ws[kq + 3][wr] = wv.w;
        }
        __syncthreads();

#pragma unroll 16
        for (int kk = 0; kk < 64; ++kk) {
            const float hval = hs[kk][ty];
            float4 w = *(const float4*)&ws[kk][tx * 4];
            acc0 += hval * w.x; acc1 += hval * w.y;
            acc2 += hval * w.z; acc3 += hval * w.w;
        }
        __syncthreads();
    }

    // Epilogue: pre = hprev + xin + acc + bh; h_new = clamp(pre, 0, 1)
    const size_t m = (size_t)mb * 16 + ty;
    const int n = nb * 64 + tx * 4;
    const size_t oidx = m * TH_ + (size_t)t * H_ + n;

    float4 xin = *(const float4*)(out + oidx);
    float4 hp  = *(const float4*)(hbase + m * hstride + n);
    float4 bv  = *(const float4*)(bh + n);

    float4 r;
    r.x = fminf(fmaxf(hp.x + xin.x + acc0 + bv.x, 0.f), 1.f);
    r.y = fminf(fmaxf(hp.y + xin.y + acc1 + bv.y, 0.f), 1.f);
    r.z = fminf(fmaxf(hp.z + xin.z + acc2 + bv.z, 0.f), 1.f);
    r.w = fminf(fmaxf(hp.w + xin.w + acc3 + bv.w, 0.f), 1.f);
    *(float4*)(out + oidx) = r;
}

// ---------------------------------------------------------------------------
// Kernel 3: copy final hidden out[:, T-1, :] -> tail of d_out [B, H].
// ---------------------------------------------------------------------------
__global__ __launch_bounds__(256) void k_copy_hidden(float* __restrict__ out)
{
    const int i = blockIdx.x * 256 + threadIdx.x;   // 0..32767 (float4 index)
    const int b = i >> 8;          // H_/4 = 256 float4 per row
    const int jq = (i & 255) * 4;
    float4 v = *(const float4*)(out + (size_t)b * TH_ + (size_t)(T_ - 1) * H_ + jq);
    *(float4*)(out + (size_t)B_ * TH_ + (size_t)b * H_ + jq) = v;
}

extern "C" void kernel_launch(void* const* d_in, const int* in_sizes, int n_in,
                              void* d_out, int out_size, void* d_ws, size_t ws_size,
                              hipStream_t stream)
{
    const float* x  = (const float*)d_in[0];
    const float* Wi = (const float*)d_in[1];
    const float* bi = (const float*)d_in[2];
    const float* Wh = (const float*)d_in[3];
    const float* bh = (const float*)d_in[4];
    const float* h0 = (const float*)d_in[5];
    float* out = (float*)d_out;

    // 1) xin = x @ Wi^T + bi  -> out[:, :, :]
    k_input_gemm<<<dim3(8, 512), 256, 0, stream>>>(x, Wi, bi, out);

    // 2) 512 recurrent steps, in place on out
    for (int t = 0; t < T_; ++t) {
        k_step<<<dim3(8, 16), 256, 0, stream>>>(Wh, bh, h0, out, t);
    }

    // 3) final hidden
    k_copy_hidden<<<128, 256, 0, stream>>>(out);
}

// Round 2
// 14813.167 us; speedup vs baseline: 1.7551x; 1.7551x over previous
//
#include <hip/hip_runtime.h>
#include <cstddef>

#define B_ 128
#define T_ 512
#define I_ 512
#define H_ 1024
#define TH_ (T_ * H_)
#define NBLK 256

// ---------------------------------------------------------------------------
// Kernel 1: xin = x @ Wi^T + bi  written into out's rnn_out region [B,T,H].
// (unchanged from round 1)
// ---------------------------------------------------------------------------
__global__ __launch_bounds__(256) void k_input_gemm(
    const float* __restrict__ A, const float* __restrict__ W,
    const float* __restrict__ bi, float* __restrict__ C)
{
    const int nb = blockIdx.x;   // 0..7
    const int mb = blockIdx.y;   // 0..511
    const int tid = threadIdx.x;
    const int tx = tid & 15;
    const int ty = tid >> 4;

    __shared__ float As[16][132];
    __shared__ float Ws[16][132];

    float acc[8][8];
#pragma unroll
    for (int i = 0; i < 8; ++i)
#pragma unroll
        for (int j = 0; j < 8; ++j) acc[i][j] = 0.f;

    const float* Ab = A + (size_t)mb * 128 * I_;
    const float* Wb = W + (size_t)nb * 128 * I_;

    for (int kt = 0; kt < I_; kt += 16) {
        {
            const int r = tid >> 2;
            const int kq = (tid & 3) * 4;
            float4 v0 = *(const float4*)(Ab + (size_t)r * I_ + kt + kq);
            float4 v1 = *(const float4*)(Ab + (size_t)(r + 64) * I_ + kt + kq);
            As[kq + 0][r] = v0.x; As[kq + 1][r] = v0.y;
            As[kq + 2][r] = v0.z; As[kq + 3][r] = v0.w;
            As[kq + 0][r + 64] = v1.x; As[kq + 1][r + 64] = v1.y;
            As[kq + 2][r + 64] = v1.z; As[kq + 3][r + 64] = v1.w;
            float4 w0 = *(const float4*)(Wb + (size_t)r * I_ + kt + kq);
            float4 w1 = *(const float4*)(Wb + (size_t)(r + 64) * I_ + kt + kq);
            Ws[kq + 0][r] = w0.x; Ws[kq + 1][r] = w0.y;
            Ws[kq + 2][r] = w0.z; Ws[kq + 3][r] = w0.w;
            Ws[kq + 0][r + 64] = w1.x; Ws[kq + 1][r + 64] = w1.y;
            Ws[kq + 2][r + 64] = w1.z; Ws[kq + 3][r + 64] = w1.w;
        }
        __syncthreads();

#pragma unroll
        for (int kk = 0; kk < 16; ++kk) {
            float4 a0 = *(const float4*)&As[kk][ty * 8];
            float4 a1 = *(const float4*)&As[kk][ty * 8 + 4];
            float4 b0 = *(const float4*)&Ws[kk][tx * 8];
            float4 b1 = *(const float4*)&Ws[kk][tx * 8 + 4];
            float av[8] = {a0.x, a0.y, a0.z, a0.w, a1.x, a1.y, a1.z, a1.w};
            float bv[8] = {b0.x, b0.y, b0.z, b0.w, b1.x, b1.y, b1.z, b1.w};
#pragma unroll
            for (int i = 0; i < 8; ++i)
#pragma unroll
                for (int j = 0; j < 8; ++j) acc[i][j] += av[i] * bv[j];
        }
        __syncthreads();
    }

    const int n0 = nb * 128 + tx * 8;
    float4 bv0 = *(const float4*)(bi + n0);
    float4 bv1 = *(const float4*)(bi + n0 + 4);
#pragma unroll
    for (int i = 0; i < 8; ++i) {
        const size_t m = (size_t)mb * 128 + ty * 8 + i;
        float4 c0, c1;
        c0.x = acc[i][0] + bv0.x; c0.y = acc[i][1] + bv0.y;
        c0.z = acc[i][2] + bv0.z; c0.w = acc[i][3] + bv0.w;
        c1.x = acc[i][4] + bv1.x; c1.y = acc[i][5] + bv1.y;
        c1.z = acc[i][6] + bv1.z; c1.w = acc[i][7] + bv1.w;
        *(float4*)(C + m * H_ + n0) = c0;
        *(float4*)(C + m * H_ + n0 + 4) = c1;
    }
}

// ---------------------------------------------------------------------------
// Kernel 2: persistent cooperative recurrence. 256 blocks x 256 threads.
// Block (bt,nt): rows m0=16*bt, cols n0=32*nt. Wave w owns cols n0+8w..+8.
// Lane (nq=lane&3, ks=lane>>2): holds Wh[na][k-slice], Wh[nb][k-slice] in
// 128 VGPRs (na=n0+8w+nq, nb=na+4; k = jj*64 + ks*4 + u). h_{t-1} staged to
// LDS each step; k-reduction via shfl_xor over ks; flat grid barrier per step.
// ---------------------------------------------------------------------------
__global__ __launch_bounds__(256, 1) void k_rnn(
    const float* __restrict__ Wh, const float* __restrict__ bh,
    const float* __restrict__ h0, float* __restrict__ out,
    unsigned* __restrict__ bar)
{
    __shared__ float hs[16][1024];   // 64 KB: h_{t-1} for this block's 16 rows

    const int bx = blockIdx.x;
    const int nt = bx & 31;
    const int bt = bx >> 5;
    const int m0 = bt * 16;
    const int n0 = nt * 32;
    const int tid = threadIdx.x;
    const int w = tid >> 6;
    const int lane = tid & 63;
    const int nq = lane & 3;
    const int ks = lane >> 2;        // 0..15

    const int na = n0 + w * 8 + nq;
    const int nb = na + 4;

    // One-time: Wh slices into registers.
    float wA[64], wB[64];
#pragma unroll
    for (int jj = 0; jj < 16; ++jj) {
        float4 a = *(const float4*)(Wh + (size_t)na * H_ + jj * 64 + ks * 4);
        float4 b = *(const float4*)(Wh + (size_t)nb * H_ + jj * 64 + ks * 4);
        wA[jj * 4 + 0] = a.x; wA[jj * 4 + 1] = a.y;
        wA[jj * 4 + 2] = a.z; wA[jj * 4 + 3] = a.w;
        wB[jj * 4 + 0] = b.x; wB[jj * 4 + 1] = b.y;
        wB[jj * 4 + 2] = b.z; wB[jj * 4 + 3] = b.w;
    }

    // Epilogue lane mapping: lane -> (rows {mm, mm+8}, col n_out).
    const int s   = lane & 7;
    const int nq2 = s & 3;
    const int ab  = (s >> 2) & 1;
    const int mm  = lane >> 3;       // 0..7
    const int n_out = n0 + w * 8 + nq2 + 4 * ab;
    const float bhv = bh[n_out];

    for (int t = 0; t < T_; ++t) {
        // ---- stage h_{t-1} into LDS (coalesced: row i, float4 col tid) ----
        const float* hb = (t == 0) ? h0
                                   : (out + (size_t)m0 * TH_ + (size_t)(t - 1) * H_);
        const size_t rstr = (t == 0) ? 0 : (size_t)TH_;
        float4 stg[16];
#pragma unroll
        for (int i = 0; i < 16; ++i)
            stg[i] = *(const float4*)(hb + (size_t)i * rstr + tid * 4);

        // xin prefetch (out[:,t,:] still holds xin; only we write our cells)
        const size_t g0 = (size_t)(m0 + mm) * TH_ + (size_t)t * H_ + n_out;
        const size_t g1 = (size_t)(m0 + mm + 8) * TH_ + (size_t)t * H_ + n_out;
        const float xin0 = out[g0];
        const float xin1 = out[g1];

#pragma unroll
        for (int i = 0; i < 16; ++i)
            *(float4*)(&hs[i][tid * 4]) = stg[i];
        __syncthreads();

        // ---- compute: 16 m-rows, each 128 FMA + ks-butterfly reduce ----
        float res0 = 0.f, res1 = 0.f;
        for (int m = 0; m < 16; ++m) {
            float a0 = 0.f, a1 = 0.f, b0 = 0.f, b1 = 0.f;
#pragma unroll
            for (int jj = 0; jj < 16; ++jj) {
                float4 h4 = *(const float4*)(&hs[m][jj * 64 + ks * 4]);
                a0 += h4.x * wA[jj * 4 + 0];
                b0 += h4.x * wB[jj * 4 + 0];
                a1 += h4.y * wA[jj * 4 + 1];
                b1 += h4.y * wB[jj * 4 + 1];
                a0 += h4.z * wA[jj * 4 + 2];
                b0 += h4.z * wB[jj * 4 + 2];
                a1 += h4.w * wA[jj * 4 + 3];
                b1 += h4.w * wB[jj * 4 + 3];
            }
            float accA = a0 + a1;
            float accB = b0 + b1;
            // reduce over ks (lane bits 2..5)
            accA += __shfl_xor(accA, 4, 64);
            accB += __shfl_xor(accB, 4, 64);
            accA += __shfl_xor(accA, 8, 64);
            accB += __shfl_xor(accB, 8, 64);
            accA += __shfl_xor(accA, 16, 64);
            accB += __shfl_xor(accB, 16, 64);
            accA += __shfl_xor(accA, 32, 64);
            accB += __shfl_xor(accB, 32, 64);
            // pick the value this lane is responsible for
            float vA = __shfl(accA, nq2, 64);
            float vB = __shfl(accB, nq2, 64);
            float want = ab ? vB : vA;
            res0 = (m == mm)     ? want : res0;
            res1 = (m == mm + 8) ? want : res1;
        }

        // ---- epilogue: pre = h + xin + Wh.h + bh; clamp to [0,1] ----
        const float hp0 = hs[mm][n_out];
        const float hp1 = hs[mm + 8][n_out];
        out[g0] = fminf(fmaxf(hp0 + xin0 + res0 + bhv, 0.f), 1.f);
        out[g1] = fminf(fmaxf(hp1 + xin1 + res1 + bhv, 0.f), 1.f);

        // ---- grid barrier (monotonic counter, 1 arrive per block) ----
        __syncthreads();
        if (tid == 0) {
            __threadfence();
            atomicAdd(bar, 1u);
            const unsigned tgt = (unsigned)(t + 1) * NBLK;
            while (__hip_atomic_load(bar, __ATOMIC_RELAXED,
                                     __HIP_MEMORY_SCOPE_AGENT) < tgt) {
                __builtin_amdgcn_s_sleep(1);
            }
            __threadfence();
        }
        __syncthreads();
    }
}

// ---------------------------------------------------------------------------
// Kernel 3: copy final hidden out[:, T-1, :] -> tail of d_out [B, H].
// ---------------------------------------------------------------------------
__global__ __launch_bounds__(256) void k_copy_hidden(float* __restrict__ out)
{
    const int i = blockIdx.x * 256 + threadIdx.x;
    const int b = i >> 8;
    const int jq = (i & 255) * 4;
    float4 v = *(const float4*)(out + (size_t)b * TH_ + (size_t)(T_ - 1) * H_ + jq);
    *(float4*)(out + (size_t)B_ * TH_ + (size_t)b * H_ + jq) = v;
}

extern "C" void kernel_launch(void* const* d_in, const int* in_sizes, int n_in,
                              void* d_out, int out_size, void* d_ws, size_t ws_size,
                              hipStream_t stream)
{
    const float* x  = (const float*)d_in[0];
    const float* Wi = (const float*)d_in[1];
    const float* bi = (const float*)d_in[2];
    const float* Wh = (const float*)d_in[3];
    const float* bh = (const float*)d_in[4];
    const float* h0 = (const float*)d_in[5];
    float* out = (float*)d_out;
    unsigned* bar = (unsigned*)d_ws;

    // zero the barrier counter (deterministic across replays)
    hipMemsetAsync(d_ws, 0, 256, stream);

    // 1) xin = x @ Wi^T + bi  -> out rnn_out region
    k_input_gemm<<<dim3(8, 512), 256, 0, stream>>>(x, Wi, bi, out);

    // 2) persistent cooperative recurrence (512 steps, 1 grid barrier each)
    void* args[] = { (void*)&Wh, (void*)&bh, (void*)&h0, (void*)&out, (void*)&bar };
    hipLaunchCooperativeKernel((const void*)k_rnn, dim3(NBLK), dim3(256),
                               args, 0, stream);

    // 3) final hidden
    k_copy_hidden<<<128, 256, 0, stream>>>(out);
}

// Round 4
// 10863.931 us; speedup vs baseline: 2.3931x; 1.3635x over previous
//
#include <hip/hip_runtime.h>
#include <cstddef>

#define B_ 128
#define T_ 512
#define I_ 512
#define H_ 1024
#define TH_ (T_ * H_)
#define PSTR 522              // partial-buffer row stride (floats)
#define LDSN (16 * PSTR)      // 8352 floats = 33.4 KB (>= 8*1024 h-stage)

// async global->LDS, 16B per lane. LDS dest = wave-uniform base + lane*16.
__device__ __forceinline__ void gload_lds16(const float* g, float* l) {
    __builtin_amdgcn_global_load_lds(
        (const __attribute__((address_space(1))) unsigned int*)g,
        (__attribute__((address_space(3))) unsigned int*)l, 16, 0, 0);
}

// ---------------------------------------------------------------------------
// Kernel 1: xin = x @ Wi^T + bi -> out rnn_out region [B,T,H]. (unchanged,
// passed rounds 1-2)
// ---------------------------------------------------------------------------
__global__ __launch_bounds__(256) void k_input_gemm(
    const float* __restrict__ A, const float* __restrict__ W,
    const float* __restrict__ bi, float* __restrict__ C)
{
    const int nb = blockIdx.x;
    const int mb = blockIdx.y;
    const int tid = threadIdx.x;
    const int tx = tid & 15;
    const int ty = tid >> 4;

    __shared__ float As[16][132];
    __shared__ float Ws[16][132];

    float acc[8][8];
#pragma unroll
    for (int i = 0; i < 8; ++i)
#pragma unroll
        for (int j = 0; j < 8; ++j) acc[i][j] = 0.f;

    const float* Ab = A + (size_t)mb * 128 * I_;
    const float* Wb = W + (size_t)nb * 128 * I_;

    for (int kt = 0; kt < I_; kt += 16) {
        {
            const int r = tid >> 2;
            const int kq = (tid & 3) * 4;
            float4 v0 = *(const float4*)(Ab + (size_t)r * I_ + kt + kq);
            float4 v1 = *(const float4*)(Ab + (size_t)(r + 64) * I_ + kt + kq);
            As[kq + 0][r] = v0.x; As[kq + 1][r] = v0.y;
            As[kq + 2][r] = v0.z; As[kq + 3][r] = v0.w;
            As[kq + 0][r + 64] = v1.x; As[kq + 1][r + 64] = v1.y;
            As[kq + 2][r + 64] = v1.z; As[kq + 3][r + 64] = v1.w;
            float4 w0 = *(const float4*)(Wb + (size_t)r * I_ + kt + kq);
            float4 w1 = *(const float4*)(Wb + (size_t)(r + 64) * I_ + kt + kq);
            Ws[kq + 0][r] = w0.x; Ws[kq + 1][r] = w0.y;
            Ws[kq + 2][r] = w0.z; Ws[kq + 3][r] = w0.w;
            Ws[kq + 0][r + 64] = w1.x; Ws[kq + 1][r + 64] = w1.y;
            Ws[kq + 2][r + 64] = w1.z; Ws[kq + 3][r + 64] = w1.w;
        }
        __syncthreads();

#pragma unroll
        for (int kk = 0; kk < 16; ++kk) {
            float4 a0 = *(const float4*)&As[kk][ty * 8];
            float4 a1 = *(const float4*)&As[kk][ty * 8 + 4];
            float4 b0 = *(const float4*)&Ws[kk][tx * 8];
            float4 b1 = *(const float4*)&Ws[kk][tx * 8 + 4];
            float av[8] = {a0.x, a0.y, a0.z, a0.w, a1.x, a1.y, a1.z, a1.w};
            float bv[8] = {b0.x, b0.y, b0.z, b0.w, b1.x, b1.y, b1.z, b1.w};
#pragma unroll
            for (int i = 0; i < 8; ++i)
#pragma unroll
                for (int j = 0; j < 8; ++j) acc[i][j] += av[i] * bv[j];
        }
        __syncthreads();
    }

    const int n0 = nb * 128 + tx * 8;
    float4 bv0 = *(const float4*)(bi + n0);
    float4 bv1 = *(const float4*)(bi + n0 + 4);
#pragma unroll
    for (int i = 0; i < 8; ++i) {
        const size_t m = (size_t)mb * 128 + ty * 8 + i;
        float4 c0, c1;
        c0.x = acc[i][0] + bv0.x; c0.y = acc[i][1] + bv0.y;
        c0.z = acc[i][2] + bv0.z; c0.w = acc[i][3] + bv0.w;
        c1.x = acc[i][4] + bv1.x; c1.y = acc[i][5] + bv1.y;
        c1.z = acc[i][6] + bv1.z; c1.w = acc[i][7] + bv1.w;
        *(float4*)(C + m * H_ + n0) = c0;
        *(float4*)(C + m * H_ + n0 + 4) = c1;
    }
}

// ---------------------------------------------------------------------------
// Kernel 2: persistent recurrence, REGULAR launch (256 blocks x 256 thr,
// 33KB LDS => capacity >=2 blocks/CU, all 256 blocks resident by dispatch).
// Block: bt=bx&15 -> rows m0=8*bt; nt=bx>>4 -> cols n0=64*nt.
// Group barrier over the 16 blocks sharing bt (same bx mod 16 => same XCD
// under round-robin dispatch). Per-lane: 4 cols x 64-k slice of Wh in
// float4 wreg[4][16] (256 VGPRs, constant-indexed).
// Per step: global_load_lds h-stage -> 2048 FMA (acc[8][4]) ->
// LDS partial-transpose reduce -> fused epilogue -> group barrier.
// ---------------------------------------------------------------------------
__global__ __launch_bounds__(256, 1) void k_rnn(
    const float* __restrict__ Wh, const float* __restrict__ bh,
    const float* __restrict__ h0, float* __restrict__ out,
    unsigned* __restrict__ bar)
{
    __shared__ float lds[LDSN];   // union: h-stage [8][1024] / partials [16][PSTR]

    const int bx = blockIdx.x;
    const int bt = bx & 15;
    const int nt = bx >> 4;
    const int m0 = bt * 8;
    const int n0 = nt * 64;
    const int tid = threadIdx.x;
    const int w = tid >> 6;
    const int lane = tid & 63;
    const int nq = lane & 3;
    const int ks = lane >> 2;       // 0..15 k-split

    // ---- one-time: Wh register-stationary: cols n0+w*16+nq+4j, j=0..3 ----
    float4 wreg[4][16];
#pragma unroll
    for (int j = 0; j < 4; ++j) {
        const float* wp = Wh + (size_t)(n0 + w * 16 + nq + 4 * j) * H_ + ks * 4;
#pragma unroll
        for (int jj = 0; jj < 16; ++jj)
            wreg[j][jj] = *(const float4*)(wp + jj * 64);
    }

    const int r  = tid >> 5;         // output row 0..7
    const int nl = 2 * (tid & 31);   // output col-local (even)
    const float2 bh2 = *(const float2*)(bh + n0 + nl);
    unsigned* mybar = bar + bt * 32; // 128 B apart

    for (int t = 0; t < T_; ++t) {
        // ---- stage h_{t-1} rows m0..m0+7 into LDS via global_load_lds ----
        const float* hb; size_t rstr;
        if (t == 0) { hb = h0; rstr = 0; }
        else        { hb = out + (size_t)(t - 1) * H_; rstr = TH_; }
        // wave w stages quarter w (256 floats) of every row p.
#pragma unroll
        for (int p = 0; p < 8; ++p) {
            const float* gp = hb + (size_t)(m0 + p) * rstr + w * 256 + lane * 4;
            gload_lds16(gp, &lds[p * 1024 + w * 256]);
        }
        // xin prefetch (own cells only)
        const size_t g0 = (size_t)(m0 + r) * TH_ + (size_t)t * H_ + n0 + nl;
        const float2 xin2 = *(const float2*)(out + g0);

        asm volatile("s_waitcnt vmcnt(0)" ::: "memory");
        __syncthreads();

        // h_prev for epilogue (read before LDS reuse)
        const float2 hp2 = *(const float2*)&lds[r * 1024 + n0 + nl];

        // ---- compute: acc[m][j] = partial dot over this lane's 64-k slice ----
        float acc[8][4];
#pragma unroll
        for (int m = 0; m < 8; ++m)
#pragma unroll
            for (int j = 0; j < 4; ++j) acc[m][j] = 0.f;

#pragma unroll
        for (int m = 0; m < 8; ++m) {
#pragma unroll
            for (int jj = 0; jj < 16; ++jj) {
                float4 h4 = *(const float4*)&lds[m * 1024 + jj * 64 + ks * 4];
#pragma unroll
                for (int j = 0; j < 4; ++j) {
                    acc[m][j] += h4.x * wreg[j][jj].x;
                    acc[m][j] += h4.y * wreg[j][jj].y;
                    acc[m][j] += h4.z * wreg[j][jj].z;
                    acc[m][j] += h4.w * wreg[j][jj].w;
                }
            }
        }
        __syncthreads();   // h reads done; LDS becomes partial buffer

        // ---- partial write: part[ks][m*64 + local_col] ----
#pragma unroll
        for (int m = 0; m < 8; ++m)
#pragma unroll
            for (int j = 0; j < 4; ++j)
                lds[PSTR * ks + m * 64 + w * 16 + nq + 4 * j] = acc[m][j];
        __syncthreads();

        // ---- reduce over 16 k-slices: thread owns flat cells 2*tid, 2*tid+1 ----
        float rx = 0.f, ry = 0.f;
#pragma unroll
        for (int g = 0; g < 16; ++g) {
            float2 p2 = *(const float2*)&lds[PSTR * g + 2 * tid];
            rx += p2.x; ry += p2.y;
        }

        // ---- epilogue: pre = h + xin + Wh.h + bh; clamp [0,1] ----
        float2 res;
        res.x = fminf(fmaxf(hp2.x + xin2.x + rx + bh2.x, 0.f), 1.f);
        res.y = fminf(fmaxf(hp2.y + xin2.y + ry + bh2.y, 0.f), 1.f);
        *(float2*)(out + g0) = res;
        if (t == T_ - 1) {
            *(float2*)(out + (size_t)B_ * TH_ + (size_t)(m0 + r) * H_ + n0 + nl) = res;
        }

        // ---- 16-block group barrier (round-2-proven pattern) ----
        __syncthreads();   // drains this block's stores (vmcnt) before arrival
        if (tid == 0) {
            __threadfence();
            atomicAdd(mybar, 1u);
            const unsigned tgt = (unsigned)(t + 1) * 16u;
            while (__hip_atomic_load(mybar, __ATOMIC_RELAXED,
                                     __HIP_MEMORY_SCOPE_AGENT) < tgt) {
                __builtin_amdgcn_s_sleep(1);
            }
            __threadfence();
        }
        __syncthreads();
    }
}

extern "C" void kernel_launch(void* const* d_in, const int* in_sizes, int n_in,
                              void* d_out, int out_size, void* d_ws, size_t ws_size,
                              hipStream_t stream)
{
    const float* x  = (const float*)d_in[0];
    const float* Wi = (const float*)d_in[1];
    const float* bi = (const float*)d_in[2];
    const float* Wh = (const float*)d_in[3];
    const float* bh = (const float*)d_in[4];
    const float* h0 = (const float*)d_in[5];
    float* out = (float*)d_out;
    unsigned* bar = (unsigned*)d_ws;

    // zero barrier counters (16 groups * 128 B spacing = 2048 B needed)
    const size_t zn = ws_size < 2048 ? ws_size : 2048;
    hipMemsetAsync(d_ws, 0, zn, stream);

    // 1) xin = x @ Wi^T + bi -> out rnn_out region
    k_input_gemm<<<dim3(8, 512), 256, 0, stream>>>(x, Wi, bi, out);

    // 2) persistent recurrence, regular launch (all 256 blocks resident:
    //    33KB LDS, 256 thr => >=2 blocks/CU capacity, grid == CU count)
    k_rnn<<<dim3(256), dim3(256), 0, stream>>>(Wh, bh, h0, out, bar);
}